// Round 7
// baseline (835.613 us; speedup 1.0000x reference)
//
#include <hip/hip_runtime.h>

// Light-field per-pixel 9x9 filter, R7.
// out[b,s,o,h,w] = clip(sum_{i,ky,kx} lf[b,s,i,3h-3+ky,3w-3+kx] * W[s,o,i,h,w,81] + bias, 0, 1)
//
// R5/R6 post-mortem: any register payload live across barriers spills (VGPR 256,
// scratch GBs). R7: lf window staged in LDS via global_load_lds (zero VGPR cost,
// contiguous L1 bursts). Boundary zeros written ONCE in prologue to chunks
// disjoint from all fills (validity constant across i). Compute = pure ds_read
// + fma. Weights keep R4's dbuf gll16. Nothing live across barriers but acc[3].

#define ST 9
#define INC 3
#define OUTC 3
#define OHH 128
#define OWW 128
#define KDIM 9
#define KK 81
#define HH 384
#define WW 384
#define HWSZ (HH*WW)          // 147456
#define WQ 32                 // w columns per block
#define SLICE (WQ*KK)         // 2592 floats = 10368 B
#define NPH (INC*OUTC)        // 9 phases
#define LFROW 128             // padded lf window floats per (ky,b); 104 used

__device__ __forceinline__ void gll16(const float* g, float* l) {
  __builtin_amdgcn_global_load_lds((const __attribute__((address_space(1))) void*)g,
                                   (__attribute__((address_space(3))) void*)l, 16, 0, 0);
}

__global__ __launch_bounds__(128) void lf_filter_kernel(
    const float* __restrict__ lf, const float* __restrict__ wts,
    const float* __restrict__ bias, float* __restrict__ out)
{
  __shared__ __align__(16) float ldsW[2][SLICE];       // 20736 B
  __shared__ __align__(16) float ldsLF[KDIM*4*LFROW];  // 18432 B; [ky][b][x]

  const int t   = threadIdx.x;
  const int wl  = t & 31;          // w within quarter (also fill chunk col)
  const int b   = t >> 5;          // batch (also fill batch)
  const int bid = blockIdx.x;
  const int wq  = bid & 3;
  const int h   = (bid >> 2) & 127;
  const int s   = bid >> 9;
  const int w   = wq*WQ + wl;
  const int ybase = 3*h - 3;

  const float* lfb = lf + (size_t)(b*ST + s)*INC*HWSZ;

  // fill geometry: thread t owns chunk (b, c=wl) of each row; 26 chunks used
  const int  x0c   = 96*wq - 4 + 4*wl;                    // chunk source x
  const bool cused = (wl < 26);
  const bool cfill = cused && (x0c >= 0) && (x0c <= WW-4); // in-bounds chunk

  const int wu = (t & ~63) * 4;    // wave-uniform LDS dest float offset

  auto stage_w = [&](int p, int bufsel) {
    const int i = p / OUTC, o = p % OUTC;
    const float* wsrc = wts + ((size_t)(((s*OUTC + o)*INC + i)*OHH + h)*OWW + wq*WQ)*KK;
    float* dst = ldsW[bufsel];
    #pragma unroll
    for (int j = 0; j < 5; ++j)
      gll16(wsrc + (size_t)(j*128 + t)*4, dst + j*512 + wu);
    if (t < 8)
      gll16(wsrc + (size_t)(640 + t)*4, dst + 2560 + wu);
  };

  auto lf_fill = [&](int i) {      // per-lane-source gll16, row-uniform skip
    const float* src = lfb + (size_t)i*HWSZ + x0c;
    #pragma unroll
    for (int j = 0; j < KDIM; ++j) {
      const int y = ybase + j;     // block-uniform
      if ((unsigned)y < (unsigned)HH) {
        if (cfill)                 // exec-masked lanes: no LDS write
          gll16(src + (size_t)y*WW, ldsLF + j*512 + wu);
      }
    }
  };

  // ---- prologue: zero pads ONCE (disjoint from fills, constant across i) ----
  {
    float4* LF4 = reinterpret_cast<float4*>(ldsLF);
    #pragma unroll
    for (int j = 0; j < KDIM; ++j) {
      const int y = ybase + j;
      const bool row_ok = (unsigned)y < (unsigned)HH;
      if (cused && (!row_ok || !cfill))
        LF4[j*32 + t] = make_float4(0.f, 0.f, 0.f, 0.f);
    }
  }
  stage_w(0, 0);
  lf_fill(0);
  __syncthreads();   // drains ds_writes + both gll streams

  float acc[OUTC] = {0.f, 0.f, 0.f};

  #pragma unroll
  for (int p = 0; p < NPH; ++p) {
    const int o = p % OUTC;
    if (p + 1 < NPH) stage_w(p + 1, (p + 1) & 1);   // in flight during compute

    // ---- compute phase p: pure LDS + FMA ----
    const float* wrow = &ldsW[p & 1][wl*KK];        // stride 81: conflict-free
    const float* lp   = &ldsLF[b*LFROW + 3*wl + 1]; // stride 3: conflict-free
    float a0 = 0.f, a1 = 0.f, a2 = 0.f;
    #pragma unroll
    for (int ky = 0; ky < KDIM; ++ky) {
      #pragma unroll
      for (int kx = 0; kx < KDIM; ++kx) {
        const float lv = lp[ky*4*LFROW + kx];
        const float wv = wrow[ky*KDIM + kx];
        if (kx % 3 == 0)      a0 = fmaf(lv, wv, a0);
        else if (kx % 3 == 1) a1 = fmaf(lv, wv, a1);
        else                  a2 = fmaf(lv, wv, a2);
      }
    }
    acc[o] += (a0 + a1) + a2;

    if (p + 1 < NPH) __syncthreads();               // next W buf landed; cur free
    if (o == OUTC - 1 && p + 1 < NPH) {             // i boundary: refill lf window
      lf_fill(p / OUTC + 1);
      __syncthreads();                              // exposed fill (2x per block)
    }
  }

  // ---- epilogue: bias + clip + coalesced stores ----
  #pragma unroll
  for (int o = 0; o < OUTC; ++o) {
    const float bv = bias[((s*OUTC + o)*OHH + h)*OWW + w];
    float r = acc[o] + bv;
    r = r < 0.f ? 0.f : (r > 1.f ? 1.f : r);
    out[(((size_t)(b*ST + s)*OUTC + o)*OHH + h)*OWW + w] = r;
  }
}

extern "C" void kernel_launch(void* const* d_in, const int* in_sizes, int n_in,
                              void* d_out, int out_size, void* d_ws, size_t ws_size,
                              hipStream_t stream) {
  const float* lf   = (const float*)d_in[0];
  const float* wts  = (const float*)d_in[1];
  const float* bias = (const float*)d_in[2];
  float* out = (float*)d_out;
  dim3 grid(ST * OHH * 4);   // 4608 blocks: (s, h, w-quarter)
  dim3 block(128);           // (w:32) x (batch:4)
  hipLaunchKernelGGL(lf_filter_kernel, grid, block, 0, stream, lf, wts, bias, out);
}

// Round 8
// 125.171 us; speedup vs baseline: 6.6758x; 6.6758x over previous
//
#include <hip/hip_runtime.h>

// Light-field per-pixel 9x9 filter, R8.
// out[b,s,o,h,w] = clip(sum_{i,ky,kx} lf[b,s,i,3h-3+ky,3w-3+kx] * W[s,o,i,h,w,81] + bias, 0, 1)
//
// R4 (194us, VGPR 48) = best prior. Its cost: 729 scalar lf gathers/thread
// (lf fetched 3x, once per o) + barrier-serialized phases. R5-R7 post-mortems:
// big unrolled bodies or cross-barrier payloads -> VGPR 256 + GB-scale scratch.
// R8: o innermost over a 9-float lf register row (lives inside one ky iter,
// never crosses barriers); 3 weight slices co-resident in LDS (31.1 KB,
// 5 blocks/CU); i and ky are RUNTIME loops -> small straight-line bodies.
// lf gathers: 729 -> 243/thread. Weight staging = R4's proven gll16 pattern x3.

#define ST 9
#define INC 3
#define OUTC 3
#define OHH 128
#define OWW 128
#define KDIM 9
#define KK 81
#define HH 384
#define WW 384
#define HWSZ (HH*WW)          // 147456
#define WQ 32                 // w columns per block
#define SLICE (WQ*KK)         // 2592 floats = 10368 B per (s,o,i,h,w-quarter)

__device__ __forceinline__ void gll16(const float* g, float* l) {
  __builtin_amdgcn_global_load_lds((const __attribute__((address_space(1))) void*)g,
                                   (__attribute__((address_space(3))) void*)l, 16, 0, 0);
}

__global__ __launch_bounds__(128) void lf_filter_kernel(
    const float* __restrict__ lf, const float* __restrict__ wts,
    const float* __restrict__ bias, float* __restrict__ out)
{
  __shared__ __align__(16) float ldsW[OUTC][SLICE];   // 31104 B -> 5 blocks/CU

  const int t   = threadIdx.x;
  const int wl  = t & 31;          // w within quarter
  const int b   = t >> 5;          // batch
  const int bid = blockIdx.x;
  const int wq  = bid & 3;
  const int h   = (bid >> 2) & 127;
  const int s   = bid >> 9;
  const int w   = wq*WQ + wl;
  const int xbase = 3*w - 3;
  const int ybase = 3*h - 3;

  const float* lfb = lf + (size_t)(b*ST + s)*INC*HWSZ;

  // clamped x indices + masks (static-indexed under unroll -> VGPRs)
  int   xi[KDIM];
  float xm[KDIM];
  #pragma unroll
  for (int kx = 0; kx < KDIM; ++kx) {
    const int x = xbase + kx;
    xi[kx] = x < 0 ? 0 : (x > WW-1 ? WW-1 : x);
    xm[kx] = ((unsigned)x < (unsigned)WW) ? 1.f : 0.f;
  }

  const int wu = (t & ~63) * 4;    // wave-uniform LDS dest float offset

  float acc[OUTC] = {0.f, 0.f, 0.f};

  #pragma unroll 1
  for (int i = 0; i < INC; ++i) {
    __syncthreads();   // waves done reading ldsW from previous i (no-op at i=0)

    // ---- stage the 3 o-slices for this i (R4's proven pattern x3) ----
    #pragma unroll
    for (int o = 0; o < OUTC; ++o) {
      const float* wsrc = wts + ((size_t)(((s*OUTC + o)*INC + i)*OHH + h)*OWW + wq*WQ)*KK;
      float* dst = ldsW[o];
      #pragma unroll
      for (int j = 0; j < 5; ++j)
        gll16(wsrc + (size_t)(j*128 + t)*4, dst + j*512 + wu);
      if (t < 8)
        gll16(wsrc + (size_t)(640 + t)*4, dst + 2560 + wu);
    }
    __syncthreads();   // drain vmcnt: all 3 slices landed

    // ---- compute: per ky, 9 lf regs reused across the 3 o's ----
    const float* lfr = lfb + (size_t)i*HWSZ;
    const int wb = wl*KK;
    #pragma unroll 1
    for (int ky = 0; ky < KDIM; ++ky) {
      const int y = ybase + ky;          // block-uniform -> scalar branch
      if ((unsigned)y < (unsigned)HH) {
        const float* rowp = lfr + (size_t)y*WW;
        float lv[KDIM];
        #pragma unroll
        for (int kx = 0; kx < KDIM; ++kx) lv[kx] = rowp[xi[kx]] * xm[kx];
        #pragma unroll
        for (int o = 0; o < OUTC; ++o) {
          const float* wrow = &ldsW[o][wb + ky*KDIM];   // lane stride 81: conflict-free
          float a = acc[o];
          #pragma unroll
          for (int kx = 0; kx < KDIM; ++kx)
            a = fmaf(lv[kx], wrow[kx], a);
          acc[o] = a;
        }
      }
    }
  }

  // ---- epilogue: bias + clip + coalesced stores ----
  #pragma unroll
  for (int o = 0; o < OUTC; ++o) {
    const float bv = bias[((s*OUTC + o)*OHH + h)*OWW + w];
    float r = acc[o] + bv;
    r = r < 0.f ? 0.f : (r > 1.f ? 1.f : r);
    out[(((size_t)(b*ST + s)*OUTC + o)*OHH + h)*OWW + w] = r;
  }
}

extern "C" void kernel_launch(void* const* d_in, const int* in_sizes, int n_in,
                              void* d_out, int out_size, void* d_ws, size_t ws_size,
                              hipStream_t stream) {
  const float* lf   = (const float*)d_in[0];
  const float* wts  = (const float*)d_in[1];
  const float* bias = (const float*)d_in[2];
  float* out = (float*)d_out;
  dim3 grid(ST * OHH * 4);   // 4608 blocks: (s, h, w-quarter)
  dim3 block(128);           // (w:32) x (batch:4)
  hipLaunchKernelGGL(lf_filter_kernel, grid, block, 0, stream, lf, wts, bias, out);
}

// Round 9
// 116.698 us; speedup vs baseline: 7.1605x; 1.0726x over previous
//
#include <hip/hip_runtime.h>

// Light-field per-pixel 9x9 filter, R9.
// out[b,s,o,h,w] = clip(sum_{i,ky,kx} lf[b,s,i,3h-3+ky,3w-3+kx] * W[s,o,i,h,w,81] + bias, 0, 1)
//
// R8 (125us): o-innermost over 9-float lf register row, 3 weight slices in LDS,
// runtime i/ky loops (small bodies -> no spill). R9: vectorize the lf row read
// (2x float4 + 1 scalar from clamped dword-aligned base) -- 9 -> 3 vmem instrs
// per ky (~3x less TA) -- with branchless shift-select for the only two edge
// columns in the grid (w=0, w=127). xi/xm tables eliminated.

#define ST 9
#define INC 3
#define OUTC 3
#define OHH 128
#define OWW 128
#define KDIM 9
#define KK 81
#define HH 384
#define WW 384
#define HWSZ (HH*WW)          // 147456
#define WQ 32                 // w columns per block
#define SLICE (WQ*KK)         // 2592 floats = 10368 B per (s,o,i,h,w-quarter)

typedef float f32x4 __attribute__((ext_vector_type(4)));
struct __attribute__((packed, aligned(4))) U4 { f32x4 v; };  // align-4 vector load

__device__ __forceinline__ void gll16(const float* g, float* l) {
  __builtin_amdgcn_global_load_lds((const __attribute__((address_space(1))) void*)g,
                                   (__attribute__((address_space(3))) void*)l, 16, 0, 0);
}

__global__ __launch_bounds__(128) void lf_filter_kernel(
    const float* __restrict__ lf, const float* __restrict__ wts,
    const float* __restrict__ bias, float* __restrict__ out)
{
  __shared__ __align__(16) float ldsW[OUTC][SLICE];   // 31104 B -> 5 blocks/CU

  const int t   = threadIdx.x;
  const int wl  = t & 31;          // w within quarter
  const int b   = t >> 5;          // batch
  const int bid = blockIdx.x;
  const int wq  = bid & 3;
  const int h   = (bid >> 2) & 127;
  const int s   = bid >> 9;
  const int w   = wq*WQ + wl;
  const int xbase = 3*w - 3;
  const int ybase = 3*h - 3;

  // clamped vector-load base + edge shift (nonzero only for w=0 / w=127)
  const int  base  = xbase < 0 ? 0 : (xbase > WW-KDIM ? WW-KDIM : xbase);
  const bool s_neg = (xbase < base);   // w==0   : lv[kx] = kx>=3 ? raw[kx-3] : 0
  const bool s_pos = (xbase > base);   // w==127 : lv[kx] = kx<=5 ? raw[kx+3] : 0

  const float* lfb = lf + (size_t)(b*ST + s)*INC*HWSZ;
  const int wu = (t & ~63) * 4;    // wave-uniform LDS dest float offset

  float acc[OUTC] = {0.f, 0.f, 0.f};

  #pragma unroll 1
  for (int i = 0; i < INC; ++i) {
    __syncthreads();   // waves done reading ldsW from previous i (no-op at i=0)

    // ---- stage the 3 o-slices for this i (proven gll16 pattern x3) ----
    #pragma unroll
    for (int o = 0; o < OUTC; ++o) {
      const float* wsrc = wts + ((size_t)(((s*OUTC + o)*INC + i)*OHH + h)*OWW + wq*WQ)*KK;
      float* dst = ldsW[o];
      #pragma unroll
      for (int j = 0; j < 5; ++j)
        gll16(wsrc + (size_t)(j*128 + t)*4, dst + j*512 + wu);
      if (t < 8)
        gll16(wsrc + (size_t)(640 + t)*4, dst + 2560 + wu);
    }
    __syncthreads();   // drain vmcnt: all 3 slices landed

    // ---- compute: per ky, vector-load 9 lf floats, reuse across 3 o's ----
    const float* lfr = lfb + (size_t)i*HWSZ;
    const int wb = wl*KK;
    #pragma unroll 1
    for (int ky = 0; ky < KDIM; ++ky) {
      const int y = ybase + ky;          // block-uniform -> scalar branch
      if ((unsigned)y < (unsigned)HH) {
        const float* rp = lfr + (size_t)y*WW + base;
        const f32x4 va = reinterpret_cast<const U4*>(rp)->v;      // raw[0..3]
        const f32x4 vb = reinterpret_cast<const U4*>(rp + 4)->v;  // raw[4..7]
        const float rc = rp[8];                                   // raw[8]
        const float raw[KDIM] = {va.x, va.y, va.z, va.w, vb.x, vb.y, vb.z, vb.w, rc};
        float lv[KDIM];
        #pragma unroll
        for (int kx = 0; kx < KDIM; ++kx) {
          const float nv = (kx >= 3) ? raw[kx-3] : 0.f;   // shift -3 view
          const float pv = (kx <= 5) ? raw[kx+3] : 0.f;   // shift +3 view
          lv[kx] = s_neg ? nv : (s_pos ? pv : raw[kx]);
        }
        #pragma unroll
        for (int o = 0; o < OUTC; ++o) {
          const float* wrow = &ldsW[o][wb + ky*KDIM];   // lane stride 81: conflict-free
          float a = acc[o];
          #pragma unroll
          for (int kx = 0; kx < KDIM; ++kx)
            a = fmaf(lv[kx], wrow[kx], a);
          acc[o] = a;
        }
      }
    }
  }

  // ---- epilogue: bias + clip + coalesced stores ----
  #pragma unroll
  for (int o = 0; o < OUTC; ++o) {
    const float bv = bias[((s*OUTC + o)*OHH + h)*OWW + w];
    float r = acc[o] + bv;
    r = r < 0.f ? 0.f : (r > 1.f ? 1.f : r);
    out[(((size_t)(b*ST + s)*OUTC + o)*OHH + h)*OWW + w] = r;
  }
}

extern "C" void kernel_launch(void* const* d_in, const int* in_sizes, int n_in,
                              void* d_out, int out_size, void* d_ws, size_t ws_size,
                              hipStream_t stream) {
  const float* lf   = (const float*)d_in[0];
  const float* wts  = (const float*)d_in[1];
  const float* bias = (const float*)d_in[2];
  float* out = (float*)d_out;
  dim3 grid(ST * OHH * 4);   // 4608 blocks: (s, h, w-quarter)
  dim3 block(128);           // (w:32) x (batch:4)
  hipLaunchKernelGGL(lf_filter_kernel, grid, block, 0, stream, lf, wts, bias, out);
}

// Round 10
// 103.248 us; speedup vs baseline: 8.0932x; 1.1303x over previous
//
#include <hip/hip_runtime.h>

// Light-field per-pixel 9x9 filter, R10.
// out[b,s,o,h,w] = clip(sum_{i,ky,kx} lf[b,s,i,3h-3+ky,3w-3+kx] * W[s,o,i,h,w,81] + bias, 0, 1)
//
// R9 (117us): 10 waves/CU, hbm 4.2/6.3 TB/s -> latency-bound on i-boundary
// drains. R10: ky-split across two half-blocks (256 thr = w:32 x b:4 x kh:2)
// sharing the SAME 3 LDS weight slices -> 31.1 KB, 5 blocks/CU, 20 waves/CU.
// kh=0: ky 0..4, kh=1: ky 5..8; partials combined via LDS (reused ldsW) at end.
// Data path identical to R9 (vectorized lf row + shift-select edges).

#define ST 9
#define INC 3
#define OUTC 3
#define OHH 128
#define OWW 128
#define KDIM 9
#define KK 81
#define HH 384
#define WW 384
#define HWSZ (HH*WW)          // 147456
#define WQ 32                 // w columns per block
#define SLICE (WQ*KK)         // 2592 floats = 10368 B per (s,o,i,h,w-quarter)

typedef float f32x4 __attribute__((ext_vector_type(4)));
struct __attribute__((packed, aligned(4))) U4 { f32x4 v; };  // align-4 vector load

__device__ __forceinline__ void gll16(const float* g, float* l) {
  __builtin_amdgcn_global_load_lds((const __attribute__((address_space(1))) void*)g,
                                   (__attribute__((address_space(3))) void*)l, 16, 0, 0);
}

__global__ __launch_bounds__(256) void lf_filter_kernel(
    const float* __restrict__ lf, const float* __restrict__ wts,
    const float* __restrict__ bias, float* __restrict__ out)
{
  __shared__ __align__(16) float ldsW[OUTC][SLICE];   // 31104 B -> 5 blocks/CU

  const int t   = threadIdx.x;
  const int wl  = t & 31;          // w within quarter
  const int b   = (t >> 5) & 3;    // batch
  const int kh  = t >> 7;          // ky half: 0 -> ky 0..4, 1 -> ky 5..8
  const int bid = blockIdx.x;
  const int wq  = bid & 3;
  const int h   = (bid >> 2) & 127;
  const int s   = bid >> 9;
  const int w   = wq*WQ + wl;
  const int xbase = 3*w - 3;
  const int ybase = 3*h - 3;

  // clamped vector-load base + edge shift (nonzero only for w=0 / w=127)
  const int  base  = xbase < 0 ? 0 : (xbase > WW-KDIM ? WW-KDIM : xbase);
  const bool s_neg = (xbase < base);
  const bool s_pos = (xbase > base);

  const float* lfb = lf + (size_t)(b*ST + s)*INC*HWSZ;
  const int wu = (t & ~63) * 4;    // wave-uniform LDS dest float offset

  const int ky0 = kh ? 5 : 0;
  const int ky1 = kh ? 9 : 5;

  float acc[OUTC] = {0.f, 0.f, 0.f};

  #pragma unroll 1
  for (int i = 0; i < INC; ++i) {
    __syncthreads();   // all waves done reading ldsW from previous i

    // ---- stage the 3 o-slices with all 256 threads ----
    #pragma unroll
    for (int o = 0; o < OUTC; ++o) {
      const float* wsrc = wts + ((size_t)(((s*OUTC + o)*INC + i)*OHH + h)*OWW + wq*WQ)*KK;
      float* dst = ldsW[o];
      #pragma unroll
      for (int j = 0; j < 2; ++j)                       // 512 float4 chunks
        gll16(wsrc + (size_t)(j*256 + t)*4, dst + j*1024 + wu);
      if (t < 136)                                      // tail: chunks 512..647
        gll16(wsrc + (size_t)(512 + t)*4, dst + 2048 + wu);
    }
    __syncthreads();   // drain vmcnt: all 3 slices landed

    // ---- compute this thread's ky range; lf row reused across the 3 o's ----
    const float* lfr = lfb + (size_t)i*HWSZ;
    const int wb = wl*KK;
    #pragma unroll 1
    for (int ky = ky0; ky < ky1; ++ky) {
      const int y = ybase + ky;          // wave-uniform branch
      if ((unsigned)y < (unsigned)HH) {
        const float* rp = lfr + (size_t)y*WW + base;
        const f32x4 va = reinterpret_cast<const U4*>(rp)->v;
        const f32x4 vb = reinterpret_cast<const U4*>(rp + 4)->v;
        const float rc = rp[8];
        const float raw[KDIM] = {va.x, va.y, va.z, va.w, vb.x, vb.y, vb.z, vb.w, rc};
        float lv[KDIM];
        #pragma unroll
        for (int kx = 0; kx < KDIM; ++kx) {
          const float nv = (kx >= 3) ? raw[kx-3] : 0.f;
          const float pv = (kx <= 5) ? raw[kx+3] : 0.f;
          lv[kx] = s_neg ? nv : (s_pos ? pv : raw[kx]);
        }
        #pragma unroll
        for (int o = 0; o < OUTC; ++o) {
          const float* wrow = &ldsW[o][wb + ky*KDIM];   // lane stride 81: conflict-free
          float a = acc[o];
          #pragma unroll
          for (int kx = 0; kx < KDIM; ++kx)
            a = fmaf(lv[kx], wrow[kx], a);
          acc[o] = a;
        }
      }
    }
  }

  // ---- combine ky-halves via LDS (reuse ldsW), then epilogue by kh=0 ----
  float* part = (float*)ldsW;       // 128*3 floats, stride-3: conflict-free
  __syncthreads();                  // everyone done reading weights
  if (kh == 1) {
    const int q = t & 127;
    #pragma unroll
    for (int o = 0; o < OUTC; ++o) part[q*3 + o] = acc[o];
  }
  __syncthreads();
  if (kh == 0) {
    #pragma unroll
    for (int o = 0; o < OUTC; ++o) {
      const float bv = bias[((s*OUTC + o)*OHH + h)*OWW + w];
      float r = acc[o] + part[t*3 + o] + bv;
      r = r < 0.f ? 0.f : (r > 1.f ? 1.f : r);
      out[(((size_t)(b*ST + s)*OUTC + o)*OHH + h)*OWW + w] = r;
    }
  }
}

extern "C" void kernel_launch(void* const* d_in, const int* in_sizes, int n_in,
                              void* d_out, int out_size, void* d_ws, size_t ws_size,
                              hipStream_t stream) {
  const float* lf   = (const float*)d_in[0];
  const float* wts  = (const float*)d_in[1];
  const float* bias = (const float*)d_in[2];
  float* out = (float*)d_out;
  dim3 grid(ST * OHH * 4);   // 4608 blocks: (s, h, w-quarter)
  dim3 block(256);           // (w:32) x (batch:4) x (ky-half:2)
  hipLaunchKernelGGL(lf_filter_kernel, grid, block, 0, stream, lf, wts, bias, out);
}

// Round 11
// 99.978 us; speedup vs baseline: 8.3580x; 1.0327x over previous
//
#include <hip/hip_runtime.h>

// Light-field per-pixel 9x9 filter, R11.
// out[b,s,o,h,w] = clip(sum_{i,ky,kx} lf[b,s,i,3h-3+ky,3w-3+kx] * W[s,o,i,h,w,81] + bias, 0, 1)
//
// R10 (103us): 5 blocks/CU, staging drains bunch -> HBM idles ~25%. R11: WQ=16,
// 128-thread blocks (w:16 x b:4 x kh:2), slices 15.6 KB -> 10 blocks/CU = 20
// waves/CU with 10 desynchronized staging streams (half-size drains). Data path
// identical to R10 (vectorized lf row + shift-select edges, o-innermost).

#define ST 9
#define INC 3
#define OUTC 3
#define OHH 128
#define OWW 128
#define KDIM 9
#define KK 81
#define HH 384
#define WW 384
#define HWSZ (HH*WW)          // 147456
#define WQ 16                 // w columns per block
#define SLICE (WQ*KK)         // 1296 floats = 5184 B per (s,o,i,h,w-16th)

typedef float f32x4 __attribute__((ext_vector_type(4)));
struct __attribute__((packed, aligned(4))) U4 { f32x4 v; };  // align-4 vector load

__device__ __forceinline__ void gll16(const float* g, float* l) {
  __builtin_amdgcn_global_load_lds((const __attribute__((address_space(1))) void*)g,
                                   (__attribute__((address_space(3))) void*)l, 16, 0, 0);
}

__global__ __launch_bounds__(128) void lf_filter_kernel(
    const float* __restrict__ lf, const float* __restrict__ wts,
    const float* __restrict__ bias, float* __restrict__ out)
{
  __shared__ __align__(16) float ldsW[OUTC][SLICE];   // 15552 B -> 10 blocks/CU

  const int t   = threadIdx.x;
  const int wl  = t & 15;          // w within group
  const int b   = (t >> 4) & 3;    // batch
  const int kh  = t >> 6;          // ky half: 0 -> ky 0..4, 1 -> ky 5..8
  const int bid = blockIdx.x;
  const int wg  = bid & 7;         // w group of 16
  const int h   = (bid >> 3) & 127;
  const int s   = bid >> 10;
  const int w   = wg*WQ + wl;
  const int xbase = 3*w - 3;
  const int ybase = 3*h - 3;

  // clamped vector-load base + edge shift (nonzero only for w=0 / w=127)
  const int  base  = xbase < 0 ? 0 : (xbase > WW-KDIM ? WW-KDIM : xbase);
  const bool s_neg = (xbase < base);
  const bool s_pos = (xbase > base);

  const float* lfb = lf + (size_t)(b*ST + s)*INC*HWSZ;
  const int wu = (t & ~63) * 4;    // wave-uniform LDS dest float offset

  const int ky0 = kh ? 5 : 0;
  const int ky1 = kh ? 9 : 5;

  float acc[OUTC] = {0.f, 0.f, 0.f};

  #pragma unroll 1
  for (int i = 0; i < INC; ++i) {
    __syncthreads();   // all waves done reading ldsW from previous i

    // ---- stage the 3 o-slices (324 float4 each) ----
    #pragma unroll
    for (int o = 0; o < OUTC; ++o) {
      const float* wsrc = wts + ((size_t)(((s*OUTC + o)*INC + i)*OHH + h)*OWW + wg*WQ)*KK;
      float* dst = ldsW[o];
      #pragma unroll
      for (int j = 0; j < 2; ++j)                      // 256 chunks
        gll16(wsrc + (size_t)(j*128 + t)*4, dst + j*512 + wu);
      if (t < 68)                                      // tail chunks 256..323
        gll16(wsrc + (size_t)(256 + t)*4, dst + 1024 + wu);
    }
    __syncthreads();   // drain vmcnt: all 3 slices landed

    // ---- compute this thread's ky range; lf row reused across the 3 o's ----
    const float* lfr = lfb + (size_t)i*HWSZ;
    const int wb = wl*KK;
    #pragma unroll 1
    for (int ky = ky0; ky < ky1; ++ky) {
      const int y = ybase + ky;          // wave-uniform branch
      if ((unsigned)y < (unsigned)HH) {
        const float* rp = lfr + (size_t)y*WW + base;
        const f32x4 va = reinterpret_cast<const U4*>(rp)->v;
        const f32x4 vb = reinterpret_cast<const U4*>(rp + 4)->v;
        const float rc = rp[8];
        const float raw[KDIM] = {va.x, va.y, va.z, va.w, vb.x, vb.y, vb.z, vb.w, rc};
        float lv[KDIM];
        #pragma unroll
        for (int kx = 0; kx < KDIM; ++kx) {
          const float nv = (kx >= 3) ? raw[kx-3] : 0.f;
          const float pv = (kx <= 5) ? raw[kx+3] : 0.f;
          lv[kx] = s_neg ? nv : (s_pos ? pv : raw[kx]);
        }
        #pragma unroll
        for (int o = 0; o < OUTC; ++o) {
          const float* wrow = &ldsW[o][wb + ky*KDIM];   // 17*wl mod 32: conflict-free
          float a = acc[o];
          #pragma unroll
          for (int kx = 0; kx < KDIM; ++kx)
            a = fmaf(lv[kx], wrow[kx], a);
          acc[o] = a;
        }
      }
    }
  }

  // ---- combine ky-halves via LDS (reuse ldsW), then epilogue by kh=0 ----
  float* part = (float*)ldsW;       // 64*3 floats, stride-3: conflict-free
  __syncthreads();                  // everyone done reading weights
  if (kh == 1) {
    const int q = t & 63;
    #pragma unroll
    for (int o = 0; o < OUTC; ++o) part[q*3 + o] = acc[o];
  }
  __syncthreads();
  if (kh == 0) {
    #pragma unroll
    for (int o = 0; o < OUTC; ++o) {
      const float bv = bias[((s*OUTC + o)*OHH + h)*OWW + w];
      float r = acc[o] + part[t*3 + o] + bv;
      r = r < 0.f ? 0.f : (r > 1.f ? 1.f : r);
      out[(((size_t)(b*ST + s)*OUTC + o)*OHH + h)*OWW + w] = r;
    }
  }
}

extern "C" void kernel_launch(void* const* d_in, const int* in_sizes, int n_in,
                              void* d_out, int out_size, void* d_ws, size_t ws_size,
                              hipStream_t stream) {
  const float* lf   = (const float*)d_in[0];
  const float* wts  = (const float*)d_in[1];
  const float* bias = (const float*)d_in[2];
  float* out = (float*)d_out;
  dim3 grid(ST * OHH * 8);   // 9216 blocks: (s, h, w-group)
  dim3 block(128);           // (w:16) x (batch:4) x (ky-half:2)
  hipLaunchKernelGGL(lf_filter_kernel, grid, block, 0, stream, lf, wts, bias, out);
}